// Round 1
// baseline (154729.968 us; speedup 1.0000x reference)
//
#include <hip/hip_runtime.h>
#include <math.h>

#define Bn 256
#define Sn 1024
#define Ln 32
#define En 128
#define Hn 256
#define Mn 10
#define OUTn 121
#define K1 387
#define BLK2 (Bn * 640)   // one slot of x2/x3 (rows stride 640)
#define NWG 256
#define NTHR 768

__device__ __forceinline__ float sigmoidf_(float x) {
    return 1.0f / (1.0f + __expf(-x));
}
__device__ __forceinline__ float tanhf_(float x) {
    return 1.0f - 2.0f / (__expf(2.0f * x) + 1.0f);
}
__device__ __forceinline__ float softplus_(float x) {
    return (x > 20.0f) ? x : log1pf(__expf(x));
}

// ---------------- pack (once per launch) ----------------
// W1p[r=h*4+g][384], k-order [h1(256)|wv(128)]; W1t[r] = {wx0,wx1,wx2,bias}
// WattT[k][32] (30 used); WoutT[k][128] (121 used)
__global__ __launch_bounds__(256) void pack_all(
    const float* __restrict__ Wih1, const float* __restrict__ Whh1,
    const float* __restrict__ b1,
    const float* __restrict__ Watt, const float* __restrict__ Wout,
    float* __restrict__ W1p, float* __restrict__ W1t,
    float* __restrict__ WattT, float* __restrict__ WoutT)
{
    const int bid = blockIdx.x, tid = threadIdx.x;
    if (bid < 1024) {
        int r = bid, h = r >> 2, g = r & 3, row = g * 256 + h;
        for (int k = tid; k < 384; k += 256)
            W1p[(size_t)r * 384 + k] = (k < 256) ? Whh1[row * 256 + k]
                                                 : Wih1[row * 131 + (k - 256)];
        if (tid < 3) W1t[r * 4 + tid] = Wih1[row * 131 + 128 + tid];
        if (tid == 3) W1t[r * 4 + 3] = b1[row];
    } else if (bid < 1152) {
        int idx = (bid - 1024) * 256 + tid;        // 32768 = 256*128
        int k = idx >> 7, rr = idx & 127;
        WoutT[idx] = (rr < OUTn) ? Wout[rr * Hn + k] : 0.f;
    } else {
        int idx = (bid - 1152) * 256 + tid;        // 13312 = 416*32
        if (idx < 13312) {
            int k = idx >> 5, m = idx & 31;
            WattT[idx] = (m < 30 && k < K1) ? Watt[m * K1 + k] : 0.f;
        }
    }
}

// ---------------- dot: 4 gate-rows (g-stride gs) x 4 batches, N4 float4s ----
template <int N4>
__device__ __forceinline__ void dotg(const float* __restrict__ Wb, int gs,
                                     const float* __restrict__ Xb,
                                     float (&acc)[4][4])
{
#pragma unroll 4
    for (int kk = 0; kk < N4; ++kk) {
        float4 wv[4], xv[4];
#pragma unroll
        for (int g = 0; g < 4; ++g)
            wv[g] = *(const float4*)(Wb + (size_t)g * gs + (kk << 2));
#pragma unroll
        for (int bb = 0; bb < 4; ++bb)
            xv[bb] = *(const float4*)(Xb + bb * 640 + (kk << 2));
#pragma unroll
        for (int g = 0; g < 4; ++g)
#pragma unroll
            for (int bb = 0; bb < 4; ++bb) {
                acc[g][bb] = fmaf(wv[g].x, xv[bb].x, acc[g][bb]);
                acc[g][bb] = fmaf(wv[g].y, xv[bb].y, acc[g][bb]);
                acc[g][bb] = fmaf(wv[g].z, xv[bb].z, acc[g][bb]);
                acc[g][bb] = fmaf(wv[g].w, xv[bb].w, acc[g][bb]);
            }
    }
}

// ---------------- grid barrier (monotonic epoch) ----------------
__device__ __forceinline__ void grid_sync(unsigned* arrive, unsigned* epoch,
                                          unsigned target)
{
    __syncthreads();
    if (threadIdx.x == 0) {
        __threadfence();   // agent-scope release of prior global writes
        unsigned old = __hip_atomic_fetch_add(arrive, 1u, __ATOMIC_ACQ_REL,
                                              __HIP_MEMORY_SCOPE_AGENT);
        if (old == target * NWG - 1u) {
            __hip_atomic_store(epoch, target, __ATOMIC_RELEASE,
                               __HIP_MEMORY_SCOPE_AGENT);
        } else {
            while (__hip_atomic_load(epoch, __ATOMIC_ACQUIRE,
                                     __HIP_MEMORY_SCOPE_AGENT) < target)
                __builtin_amdgcn_s_sleep(2);
        }
        __threadfence();   // acquire side: invalidate L1 before WG proceeds
    }
    __syncthreads();
}

// ---------------- persistent fused kernel ----------------
// 256 WGs x 768 threads (1 WG/CU). Per step:
//   A-phase: grp 0/1/2 = gates1(i)/gates2(i-1)/gates3(i-2)  [= old kernelA tiles]
//   grid_sync
//   B-phase: attention(i) + out(i-2) for batch w = wg        [= old kernelB]
//   grid_sync
__global__ __launch_bounds__(NTHR, 3) void fused(
    const float* __restrict__ W1p, const float* __restrict__ W1t,
    const float* __restrict__ Wih2, const float* __restrict__ Whh2,
    const float* __restrict__ b2,
    const float* __restrict__ Wih3, const float* __restrict__ Whh3,
    const float* __restrict__ b3,
    const float* __restrict__ WattT, const float* __restrict__ batt,
    const float* __restrict__ WoutT, const float* __restrict__ bout,
    const float* __restrict__ emb, const int* __restrict__ words,
    const int* __restrict__ wlen, const float* __restrict__ traj,
    float* __restrict__ x2b, float* __restrict__ x3b,
    float* __restrict__ cbuf, float* __restrict__ kap,
    float* __restrict__ out, unsigned* __restrict__ barc)
{
    const int wg  = blockIdx.x;
    const int tid = threadIdx.x;
    const int grp = tid >> 8;          // 0,1,2 = layer group for A-phase
    const int t   = tid & 255;

    __shared__ float red[3 * 4224];    // 50.7 KB (per-layer reduce buffers)
    __shared__ float attL[K1];
    __shared__ float buf[NTHR];
    __shared__ float pv[32];
    __shared__ float sal[Mn], srb[Mn], skp[Mn];
    __shared__ float phi[Ln + 1];
    __shared__ int   wintL[Ln];
    __shared__ float h3L[Hn];
    __shared__ int   lenL;

    // loop-invariant per-batch data
    if (tid < Ln) wintL[tid] = words[wg * Ln + tid];
    if (tid == 0) lenL = wlen[wg];

    // A-phase decomposition (same as old kernelA with sub = wg)
    const int ht = wg >> 3, bt = wg & 7;
    const int ks = t >> 6, tr = (t >> 3) & 7, tb = t & 7;

    unsigned* arrive = barc;
    unsigned* epoch  = barc + 16;      // separate cache line
    unsigned  bar    = 0;

    __syncthreads();

    for (int i = 0; i <= Sn + 1; ++i) {
        const int p = i & 1, q = (i + 1) & 1;

        // ================= A phase =================
        {
            const int l = grp;
            bool active;
            const float* X = nullptr; float* d1 = nullptr; float* d2 = nullptr;
            if (l == 0) {                 // gates1(i): X = x2(i-1)[0:384)
                active = (i < Sn);
                X  = x2b + (size_t)q * BLK2;
                d1 = x2b + (size_t)p * BLK2;              // h1(i) -> x2(i)[0:256)
            } else if (l == 1) {          // gates2(i-1)
                active = (i >= 1 && i <= Sn);
                X  = x2b + (size_t)q * BLK2;
                d1 = x2b + (size_t)p * BLK2 + 384;        // h2(i-1) -> x2(i)[384:)
                d2 = x3b + (size_t)q * BLK2;              //         -> x3(i-1)[0:256)
            } else {                      // gates3(i-2)
                active = (i >= 2);
                X  = x3b + (size_t)p * BLK2;              // (i-2)&1 == p
                d1 = x3b + (size_t)q * BLK2 + 384;        // h3(i-2) -> x3(i-1)[384:)
            }

            if (active) {
                float acc[4][4];
#pragma unroll
                for (int g = 0; g < 4; ++g)
#pragma unroll
                    for (int bb = 0; bb < 4; ++bb) acc[g][bb] = 0.f;

                const float* Xr = X + (size_t)(bt * 32 + tb * 4) * 640;
                const int hd = ht * 8 + tr;
                if (l == 0) {
                    dotg<24>(W1p + (size_t)(hd * 4) * 384 + ks * 96, 384,
                             Xr + ks * 96, acc);
                } else {
                    const float* Wih = (l == 1) ? Wih2 : Wih3;
                    const float* Whh = (l == 1) ? Whh2 : Whh3;
                    if (ks < 2)
                        dotg<40>(Wih + (size_t)hd * 384 + ks * 160, 256 * 384,
                                 Xr + ks * 160, acc);
                    else if (ks == 2) {
                        dotg<16>(Wih + (size_t)hd * 384 + 320, 256 * 384,
                                 Xr + 320, acc);
                        dotg<24>(Whh + (size_t)hd * 256,       256 * 256,
                                 Xr + 384, acc);
                    } else
                        dotg<40>(Whh + (size_t)hd * 256 + 96,  256 * 256,
                                 Xr + 480, acc);
                }
                float* rd = red + l * 4224;
#pragma unroll
                for (int g = 0; g < 4; ++g)
#pragma unroll
                    for (int bb = 0; bb < 4; ++bb)
                        rd[ks * 1056 + (tr * 4 + g) * 33 + tb * 4 + bb] = acc[g][bb];
            }
            __syncthreads();
            if (active) {
                const float* rd = red + l * 4224;
                const int th = t >> 5, tbb = t & 31;
                const int hg = ht * 8 + th, bg = bt * 32 + tbb;
                float g4[4];
#pragma unroll
                for (int g = 0; g < 4; ++g) {
                    int rl = (th * 4 + g) * 33 + tbb;
                    g4[g] = rd[rl] + rd[1056 + rl] + rd[2112 + rl] + rd[3168 + rl];
                }
                if (l == 0) {
                    const float* tp = traj + ((size_t)bg * Sn + i) * 3;
                    float t0 = tp[0], t1 = tp[1], t2 = tp[2];
#pragma unroll
                    for (int g = 0; g < 4; ++g) {
                        float4 wt = *(const float4*)(W1t + (size_t)(hg * 4 + g) * 4);
                        g4[g] += wt.x * t0 + wt.y * t1 + wt.z * t2 + wt.w;
                    }
                } else {
                    const float* bb_ = (l == 1) ? b2 : b3;
#pragma unroll
                    for (int g = 0; g < 4; ++g) g4[g] += bb_[(g << 8) + hg];
                }
                float I = sigmoidf_(g4[0]);
                float F = sigmoidf_(g4[1]);
                float G = tanhf_(g4[2]);
                float O = sigmoidf_(g4[3]);
                float* cp = cbuf + ((size_t)l * Bn + bg) * Hn + hg;
                float c = *cp;
                float cn = fmaf(F, c, I * G);
                *cp = cn;
                float hn = O * tanhf_(cn);
                d1[(size_t)bg * 640 + hg] = hn;
                if (d2) d2[(size_t)bg * 640 + hg] = hn;
            }
        }
        grid_sync(arrive, epoch, ++bar);

        // ================= B phase =================
        if (i < Sn) {
            const float* x2p_ = x2b + (size_t)q * BLK2 + (size_t)wg * 640;  // x2(i-1)
            const float* x2c_ = x2b + (size_t)p * BLK2 + (size_t)wg * 640;  // x2(i)
            for (int k = tid; k < K1; k += NTHR)
                attL[k] = (k < 128) ? x2p_[256 + k]                        // wv(i-1)
                        : (k < 131) ? traj[((size_t)wg * Sn + i) * 3 + (k - 128)]
                                    : x2c_[k - 131];                       // h1(i)
            __syncthreads();
            {
                int m = tid & 31, kss = tid >> 5;            // kss 0..23
                int kb = kss * 17, ke = (kb + 17 < K1) ? kb + 17 : K1;
                float s = 0.f;
                for (int k = kb; k < ke; ++k)
                    s = fmaf(WattT[k * 32 + m], attL[k], s);
                buf[tid] = s;
            }
            __syncthreads();
            if (tid < 30) {
                float s = batt[tid];
#pragma unroll
                for (int kss = 0; kss < 24; ++kss) s += buf[kss * 32 + tid];
                pv[tid] = s;
            }
            __syncthreads();
            if (tid < Mn) {
                float a   = softplus_(pv[tid]);
                float bb_ = fmaxf(softplus_(pv[10 + tid]), 0.01f);
                float kp  = kap[wg * Mn + tid] + softplus_(pv[20 + tid]) * 0.04f;
                kap[wg * Mn + tid] = kp;
                sal[tid] = a; srb[tid] = 1.0f / bb_; skp[tid] = kp;
            }
            __syncthreads();
            if (tid < Ln) {
                float ph = 0.f;
                if (tid < lenL) {
#pragma unroll
                    for (int m = 0; m < Mn; ++m) {
                        float d = skp[m] - (float)tid;
                        ph = fmaf(sal[m], __expf(-d * d * srb[m]), ph);
                    }
                }
                phi[tid] = ph;
            }
            __syncthreads();
            if (tid == 0) {
                float s = 0.f;
                for (int l = 0; l < Ln; ++l) s += phi[l];
                phi[Ln] = 1.0f / (s + 1e-8f);
            }
            __syncthreads();
            if (tid < En) {
                float inv = phi[Ln];
                float a = 0.f;
                for (int l = 0; l < Ln; ++l)
                    a = fmaf(phi[l], emb[wintL[l] * En + tid], a);
                a *= inv;
                x2b[(size_t)p * BLK2 + (size_t)wg * 640 + 256 + tid] = a;  // wv(i)
                x3b[(size_t)p * BLK2 + (size_t)wg * 640 + 256 + tid] = a;
            }
        }
        __syncthreads();
        if (i >= 2) {
            const float* h3src = x3b + (size_t)q * BLK2 + (size_t)wg * 640 + 384; // h3(i-2)
            for (int k = tid; k < Hn; k += NTHR) h3L[k] = h3src[k];
            __syncthreads();
            {
                int r = tid & 127, part = tid >> 7;          // part 0..5
                int kb = part * 43, ke = (kb + 43 < Hn) ? kb + 43 : Hn;
                float s = 0.f;
                for (int k = kb; k < ke; ++k)
                    s = fmaf(WoutT[k * 128 + r], h3L[k], s);
                buf[tid] = s;
            }
            __syncthreads();
            if (tid < OUTn) {
                float s = bout[tid];
#pragma unroll
                for (int j = 0; j < 6; ++j) s += buf[j * 128 + tid];
                out[((size_t)wg * Sn + (i - 2)) * OUTn + tid] = s;
            }
        }
        grid_sync(arrive, epoch, ++bar);
    }
}

extern "C" void kernel_launch(void* const* d_in, const int* in_sizes, int n_in,
                              void* d_out, int out_size, void* d_ws, size_t ws_size,
                              hipStream_t stream)
{
    const float* traj  = (const float*)d_in[0];
    const int*   words = (const int*)d_in[1];
    const int*   wlen  = (const int*)d_in[2];
    const float* emb   = (const float*)d_in[3];
    const float* Wih1  = (const float*)d_in[4];
    const float* Whh1  = (const float*)d_in[5];
    const float* b1    = (const float*)d_in[6];
    const float* Wih2  = (const float*)d_in[7];
    const float* Whh2  = (const float*)d_in[8];
    const float* b2    = (const float*)d_in[9];
    const float* Wih3  = (const float*)d_in[10];
    const float* Whh3  = (const float*)d_in[11];
    const float* b3    = (const float*)d_in[12];
    const float* Watt  = (const float*)d_in[13];
    const float* batt  = (const float*)d_in[14];
    const float* Wout  = (const float*)d_in[15];
    const float* bout  = (const float*)d_in[16];
    float* out = (float*)d_out;

    // ws layout (floats)
    float* ws    = (float*)d_ws;
    float* x2b   = ws;                          // 2*BLK2 = 327,680
    float* x3b   = x2b + 2 * (size_t)BLK2;      // 327,680
    float* cbuf  = x3b + 2 * (size_t)BLK2;      // 3*256*256 = 196,608
    float* kap   = cbuf + 3 * Bn * Hn;          // 2,560
    unsigned* barc = (unsigned*)(kap + Bn * Mn); // 32 uints (arrive @0, epoch @16)
    float* W1p   = kap + Bn * Mn + 32;          // 393,216
    float* W1t   = W1p + (size_t)1024 * 384;    // 4,096
    float* WattT = W1t + 4096;                  // 13,312
    float* WoutT = WattT + 13312;               // 32,768

    size_t zfloats = 4 * (size_t)BLK2 + 3 * Bn * Hn + Bn * Mn + 32;
    hipMemsetAsync(ws, 0, zfloats * sizeof(float), stream);
    pack_all<<<1204, 256, 0, stream>>>(Wih1, Whh1, b1, Watt, Wout,
                                       W1p, W1t, WattT, WoutT);

    void* args[] = {
        (void*)&W1p, (void*)&W1t, (void*)&Wih2, (void*)&Whh2, (void*)&b2,
        (void*)&Wih3, (void*)&Whh3, (void*)&b3,
        (void*)&WattT, (void*)&batt, (void*)&WoutT, (void*)&bout,
        (void*)&emb, (void*)&words, (void*)&wlen, (void*)&traj,
        (void*)&x2b, (void*)&x3b, (void*)&cbuf, (void*)&kap,
        (void*)&out, (void*)&barc
    };
    hipLaunchCooperativeKernel((void*)fused, dim3(NWG), dim3(NTHR),
                               args, 0, stream);
}

// Round 2
// 101212.885 us; speedup vs baseline: 1.5288x; 1.5288x over previous
//
#include <hip/hip_runtime.h>
#include <math.h>

#define Bn 256
#define Sn 1024
#define Ln 32
#define En 128
#define Hn 256
#define Mn 10
#define OUTn 121
#define K1 387
#define BLK2 (Bn * 640)   // one slot of x2/x3 (rows stride 640)
#define NWG 256
#define NTHR 768
#define CO 0x11           // aux cache policy: SC0|SC1 = device-coherent (gfx940+)

typedef float f32x4 __attribute__((ext_vector_type(4)));
typedef int   i32x4 __attribute__((ext_vector_type(4)));

// CK-style raw buffer intrinsics (compiler tracks them -> auto s_waitcnt)
__device__ f32x4 llvm_amdgcn_raw_buffer_load_v4f32(i32x4 rsrc, int voff, int soff, int aux) __asm("llvm.amdgcn.raw.buffer.load.v4f32");
__device__ float llvm_amdgcn_raw_buffer_load_f32(i32x4 rsrc, int voff, int soff, int aux) __asm("llvm.amdgcn.raw.buffer.load.f32");
__device__ void  llvm_amdgcn_raw_buffer_store_v4f32(f32x4 d, i32x4 rsrc, int voff, int soff, int aux) __asm("llvm.amdgcn.raw.buffer.store.v4f32");
__device__ void  llvm_amdgcn_raw_buffer_store_f32(float d, i32x4 rsrc, int voff, int soff, int aux) __asm("llvm.amdgcn.raw.buffer.store.f32");

__device__ __forceinline__ i32x4 make_srd(const void* p) {
    i32x4 r;
    r.x = (int)((unsigned long long)p & 0xFFFFFFFFull);
    r.y = (int)((unsigned long long)p >> 32);   // stride=0
    r.z = -1;                                   // num_records = 0xFFFFFFFF
    r.w = 0x00020000;                           // raw dword access
    return r;
}

__device__ __forceinline__ float sigmoidf_(float x) {
    return 1.0f / (1.0f + __expf(-x));
}
__device__ __forceinline__ float tanhf_(float x) {
    return 1.0f - 2.0f / (__expf(2.0f * x) + 1.0f);
}
__device__ __forceinline__ float softplus_(float x) {
    return (x > 20.0f) ? x : log1pf(__expf(x));
}

// ---------------- pack (once per launch) ----------------
__global__ __launch_bounds__(256) void pack_all(
    const float* __restrict__ Wih1, const float* __restrict__ Whh1,
    const float* __restrict__ b1,
    const float* __restrict__ Watt, const float* __restrict__ Wout,
    float* __restrict__ W1p, float* __restrict__ W1t,
    float* __restrict__ WattT, float* __restrict__ WoutT)
{
    const int bid = blockIdx.x, tid = threadIdx.x;
    if (bid < 1024) {
        int r = bid, h = r >> 2, g = r & 3, row = g * 256 + h;
        for (int k = tid; k < 384; k += 256)
            W1p[(size_t)r * 384 + k] = (k < 256) ? Whh1[row * 256 + k]
                                                 : Wih1[row * 131 + (k - 256)];
        if (tid < 3) W1t[r * 4 + tid] = Wih1[row * 131 + 128 + tid];
        if (tid == 3) W1t[r * 4 + 3] = b1[row];
    } else if (bid < 1152) {
        int idx = (bid - 1024) * 256 + tid;        // 32768 = 256*128
        int k = idx >> 7, rr = idx & 127;
        WoutT[idx] = (rr < OUTn) ? Wout[rr * Hn + k] : 0.f;
    } else {
        int idx = (bid - 1152) * 256 + tid;        // 13312 = 416*32
        if (idx < 13312) {
            int k = idx >> 5, m = idx & 31;
            WattT[idx] = (m < 30 && k < K1) ? Watt[m * K1 + k] : 0.f;
        }
    }
}

// ---------------- dot: 4 gate-rows x 4 batches; W cached, X device-coherent --
template <int N4>
__device__ __forceinline__ void dotg(const float* __restrict__ Wb, int gs,
                                     i32x4 xrs, int xoff,
                                     float (&acc)[4][4])
{
#pragma unroll 4
    for (int kk = 0; kk < N4; ++kk) {
        f32x4 wv[4], xv[4];
#pragma unroll
        for (int g = 0; g < 4; ++g)
            wv[g] = *(const f32x4*)(Wb + (size_t)g * gs + (kk << 2));
#pragma unroll
        for (int bb = 0; bb < 4; ++bb)
            xv[bb] = llvm_amdgcn_raw_buffer_load_v4f32(xrs, xoff + bb * 2560 + (kk << 4), 0, CO);
#pragma unroll
        for (int g = 0; g < 4; ++g)
#pragma unroll
            for (int bb = 0; bb < 4; ++bb) {
                acc[g][bb] = fmaf(wv[g].x, xv[bb].x, acc[g][bb]);
                acc[g][bb] = fmaf(wv[g].y, xv[bb].y, acc[g][bb]);
                acc[g][bb] = fmaf(wv[g].z, xv[bb].z, acc[g][bb]);
                acc[g][bb] = fmaf(wv[g].w, xv[bb].w, acc[g][bb]);
            }
    }
}

// ---------------- grid barrier: relaxed atomics, NO cache maintenance -------
// All cross-WG data moves via SC0|SC1 accesses (coherent at MALL), so the
// barrier only needs ordering: each wave drains vmcnt at __syncthreads, the
// arrive/epoch atomics are themselves device-coherent.
__device__ __forceinline__ void grid_sync(unsigned* arrive, unsigned* epoch,
                                          unsigned target)
{
    asm volatile("s_waitcnt vmcnt(0)" ::: "memory");
    __syncthreads();
    if (threadIdx.x == 0) {
        unsigned old = __hip_atomic_fetch_add(arrive, 1u, __ATOMIC_RELAXED,
                                              __HIP_MEMORY_SCOPE_AGENT);
        if (old == target * NWG - 1u) {
            __hip_atomic_store(epoch, target, __ATOMIC_RELAXED,
                               __HIP_MEMORY_SCOPE_AGENT);
        } else {
            while (__hip_atomic_load(epoch, __ATOMIC_RELAXED,
                                     __HIP_MEMORY_SCOPE_AGENT) < target)
                __builtin_amdgcn_s_sleep(2);
        }
    }
    __syncthreads();
}

// ---------------- persistent fused kernel ----------------
__global__ __launch_bounds__(NTHR, 3) void fused(
    const float* __restrict__ W1p, const float* __restrict__ W1t,
    const float* __restrict__ Wih2, const float* __restrict__ Whh2,
    const float* __restrict__ b2,
    const float* __restrict__ Wih3, const float* __restrict__ Whh3,
    const float* __restrict__ b3,
    const float* __restrict__ WattT, const float* __restrict__ batt,
    const float* __restrict__ WoutT, const float* __restrict__ bout,
    const float* __restrict__ emb, const int* __restrict__ words,
    const int* __restrict__ wlen, const float* __restrict__ traj,
    float* __restrict__ x2b, float* __restrict__ x3b,
    float* __restrict__ out, unsigned* __restrict__ barc)
{
    const int wg  = blockIdx.x;
    const int tid = threadIdx.x;
    const int grp = tid >> 8;          // 0,1,2 = layer group for A-phase
    const int t   = tid & 255;

    __shared__ float red[3 * 4224];    // 50.7 KB
    __shared__ float attL[K1];
    __shared__ float buf[NTHR];
    __shared__ float pv[32];
    __shared__ float sal[Mn], srb[Mn], skp[Mn];
    __shared__ float phi[Ln + 1];
    __shared__ int   wintL[Ln];
    __shared__ float h3L[Hn];
    __shared__ int   lenL;

    if (tid < Ln) wintL[tid] = words[wg * Ln + tid];
    if (tid == 0) lenL = wlen[wg];

    const int ht = wg >> 3, bt = wg & 7;
    const int ks = t >> 6, tr = (t >> 3) & 7, tb = t & 7;

    const i32x4 rs2 = make_srd(x2b);
    const i32x4 rs3 = make_srd(x3b);

    unsigned* arrive = barc;
    unsigned* epoch  = barc + 16;      // separate cache line
    unsigned  bar    = 0;

    float c_reg  = 0.f;    // LSTM cell state: (grp, hg, bg) fixed per thread
    float kp_reg = 0.f;    // kappa: thread tid<Mn of WG wg

    __syncthreads();

    for (int i = 0; i <= Sn + 1; ++i) {
        const int p = i & 1, q = (i + 1) & 1;

        // ================= A phase =================
        {
            const int l = grp;
            bool active;
            i32x4 d1rs = rs2, d2rs = rs3;
            int d1base = 0, d2base = 0;
            bool have2 = false;
            int xbase;                     // byte offset of X slot
            if (l == 0) {                  // gates1(i): X = x2(i-1)
                active = (i < Sn);
                xbase  = q * (BLK2 * 4);
                d1base = p * (BLK2 * 4);                 // h1(i) -> x2(i)[0:256)
            } else if (l == 1) {           // gates2(i-1)
                active = (i >= 1 && i <= Sn);
                xbase  = q * (BLK2 * 4);
                d1base = p * (BLK2 * 4) + 384 * 4;       // h2(i-1) -> x2(i)[384:)
                d2base = q * (BLK2 * 4);                 //         -> x3(i-1)[0:256)
                have2  = true;
            } else {                       // gates3(i-2)
                active = (i >= 2);
                xbase  = p * (BLK2 * 4);                 // (i-2)&1 == p
                d1rs   = rs3;
                d1base = q * (BLK2 * 4) + 384 * 4;       // h3(i-2) -> x3(i-1)[384:)
            }

            if (active) {
                float acc[4][4];
#pragma unroll
                for (int g = 0; g < 4; ++g)
#pragma unroll
                    for (int bb = 0; bb < 4; ++bb) acc[g][bb] = 0.f;

                const int xrow = xbase + (bt * 32 + tb * 4) * 2560;
                const int hd = ht * 8 + tr;
                if (l == 0) {
                    dotg<24>(W1p + (size_t)(hd * 4) * 384 + ks * 96, 384,
                             rs2, xrow + ks * 384, acc);
                } else {
                    const float* Wih = (l == 1) ? Wih2 : Wih3;
                    const float* Whh = (l == 1) ? Whh2 : Whh3;
                    const i32x4 xrs = (l == 1) ? rs2 : rs3;
                    if (ks < 2)
                        dotg<40>(Wih + (size_t)hd * 384 + ks * 160, 256 * 384,
                                 xrs, xrow + ks * 640, acc);
                    else if (ks == 2) {
                        dotg<16>(Wih + (size_t)hd * 384 + 320, 256 * 384,
                                 xrs, xrow + 1280, acc);  // floats [320,384)
                        dotg<24>(Whh + (size_t)hd * 256,       256 * 256,
                                 xrs, xrow + 1536, acc);  // floats [384,480)
                    } else
                        dotg<40>(Whh + (size_t)hd * 256 + 96,  256 * 256,
                                 xrs, xrow + 1920, acc);  // floats [480,640)
                }
                float* rd = red + l * 4224;
#pragma unroll
                for (int g = 0; g < 4; ++g)
#pragma unroll
                    for (int bb = 0; bb < 4; ++bb)
                        rd[ks * 1056 + (tr * 4 + g) * 33 + tb * 4 + bb] = acc[g][bb];
            }
            __syncthreads();
            if (active) {
                const float* rd = red + l * 4224;
                const int th = t >> 5, tbb = t & 31;
                const int hg = ht * 8 + th, bg = bt * 32 + tbb;
                float g4[4];
#pragma unroll
                for (int g = 0; g < 4; ++g) {
                    int rl = (th * 4 + g) * 33 + tbb;
                    g4[g] = rd[rl] + rd[1056 + rl] + rd[2112 + rl] + rd[3168 + rl];
                }
                if (l == 0) {
                    const float* tp = traj + ((size_t)bg * Sn + i) * 3;
                    float t0 = tp[0], t1 = tp[1], t2 = tp[2];
#pragma unroll
                    for (int g = 0; g < 4; ++g) {
                        f32x4 wt = *(const f32x4*)(W1t + (size_t)(hg * 4 + g) * 4);
                        g4[g] += wt.x * t0 + wt.y * t1 + wt.z * t2 + wt.w;
                    }
                } else {
                    const float* bb_ = (l == 1) ? b2 : b3;
#pragma unroll
                    for (int g = 0; g < 4; ++g) g4[g] += bb_[(g << 8) + hg];
                }
                float I = sigmoidf_(g4[0]);
                float F = sigmoidf_(g4[1]);
                float G = tanhf_(g4[2]);
                float O = sigmoidf_(g4[3]);
                float cn = fmaf(F, c_reg, I * G);
                c_reg = cn;
                float hn = O * tanhf_(cn);
                int hoff = (bg * 640 + hg) * 4;
                llvm_amdgcn_raw_buffer_store_f32(hn, d1rs, d1base + hoff, 0, CO);
                if (have2)
                    llvm_amdgcn_raw_buffer_store_f32(hn, d2rs, d2base + hoff, 0, CO);
            }
        }
        grid_sync(arrive, epoch, ++bar);

        // ================= B phase =================
        if (i < Sn) {
            for (int k = tid; k < K1; k += NTHR) {
                float v;
                if (k < 128)                                      // wv(i-1)
                    v = llvm_amdgcn_raw_buffer_load_f32(
                            rs2, (q * BLK2 + wg * 640 + 256 + k) * 4, 0, CO);
                else if (k < 131)
                    v = traj[((size_t)wg * Sn + i) * 3 + (k - 128)];
                else                                              // h1(i)
                    v = llvm_amdgcn_raw_buffer_load_f32(
                            rs2, (p * BLK2 + wg * 640 + (k - 131)) * 4, 0, CO);
                attL[k] = v;
            }
            __syncthreads();
            {
                int m = tid & 31, kss = tid >> 5;            // kss 0..23
                int kb = kss * 17, ke = (kb + 17 < K1) ? kb + 17 : K1;
                float s = 0.f;
                for (int k = kb; k < ke; ++k)
                    s = fmaf(WattT[k * 32 + m], attL[k], s);
                buf[tid] = s;
            }
            __syncthreads();
            if (tid < 30) {
                float s = batt[tid];
#pragma unroll
                for (int kss = 0; kss < 24; ++kss) s += buf[kss * 32 + tid];
                pv[tid] = s;
            }
            __syncthreads();
            if (tid < Mn) {
                float a   = softplus_(pv[tid]);
                float bb_ = fmaxf(softplus_(pv[10 + tid]), 0.01f);
                kp_reg += softplus_(pv[20 + tid]) * 0.04f;
                sal[tid] = a; srb[tid] = 1.0f / bb_; skp[tid] = kp_reg;
            }
            __syncthreads();
            if (tid < Ln) {
                float ph = 0.f;
                if (tid < lenL) {
#pragma unroll
                    for (int m = 0; m < Mn; ++m) {
                        float d = skp[m] - (float)tid;
                        ph = fmaf(sal[m], __expf(-d * d * srb[m]), ph);
                    }
                }
                phi[tid] = ph;
            }
            __syncthreads();
            if (tid == 0) {
                float s = 0.f;
                for (int l = 0; l < Ln; ++l) s += phi[l];
                phi[Ln] = 1.0f / (s + 1e-8f);
            }
            __syncthreads();
            if (tid < En) {
                float inv = phi[Ln];
                float a = 0.f;
                for (int l = 0; l < Ln; ++l)
                    a = fmaf(phi[l], emb[wintL[l] * En + tid], a);
                a *= inv;
                int wvoff = (p * BLK2 + wg * 640 + 256 + tid) * 4;
                llvm_amdgcn_raw_buffer_store_f32(a, rs2, wvoff, 0, CO);  // wv(i)
                llvm_amdgcn_raw_buffer_store_f32(a, rs3, wvoff, 0, CO);
            }
        }
        __syncthreads();
        if (i >= 2) {
            for (int k = tid; k < Hn; k += NTHR)
                h3L[k] = llvm_amdgcn_raw_buffer_load_f32(
                             rs3, (q * BLK2 + wg * 640 + 384 + k) * 4, 0, CO);
            __syncthreads();
            {
                int r = tid & 127, part = tid >> 7;          // part 0..5
                int kb = part * 43, ke = (kb + 43 < Hn) ? kb + 43 : Hn;
                float s = 0.f;
                for (int k = kb; k < ke; ++k)
                    s = fmaf(WoutT[k * 128 + r], h3L[k], s);
                buf[tid] = s;
            }
            __syncthreads();
            if (tid < OUTn) {
                float s = bout[tid];
#pragma unroll
                for (int j = 0; j < 6; ++j) s += buf[j * 128 + tid];
                out[((size_t)wg * Sn + (i - 2)) * OUTn + tid] = s;
            }
        }
        grid_sync(arrive, epoch, ++bar);
    }
}

extern "C" void kernel_launch(void* const* d_in, const int* in_sizes, int n_in,
                              void* d_out, int out_size, void* d_ws, size_t ws_size,
                              hipStream_t stream)
{
    const float* traj  = (const float*)d_in[0];
    const int*   words = (const int*)d_in[1];
    const int*   wlen  = (const int*)d_in[2];
    const float* emb   = (const float*)d_in[3];
    const float* Wih1  = (const float*)d_in[4];
    const float* Whh1  = (const float*)d_in[5];
    const float* b1    = (const float*)d_in[6];
    const float* Wih2  = (const float*)d_in[7];
    const float* Whh2  = (const float*)d_in[8];
    const float* b2    = (const float*)d_in[9];
    const float* Wih3  = (const float*)d_in[10];
    const float* Whh3  = (const float*)d_in[11];
    const float* b3    = (const float*)d_in[12];
    const float* Watt  = (const float*)d_in[13];
    const float* batt  = (const float*)d_in[14];
    const float* Wout  = (const float*)d_in[15];
    const float* bout  = (const float*)d_in[16];
    float* out = (float*)d_out;

    // ws layout (floats)
    float* ws    = (float*)d_ws;
    float* x2b   = ws;                          // 2*BLK2 = 327,680
    float* x3b   = x2b + 2 * (size_t)BLK2;      // 327,680
    unsigned* barc = (unsigned*)(x3b + 2 * (size_t)BLK2); // 32 uints
    float* W1p   = x3b + 2 * (size_t)BLK2 + 32; // 393,216
    float* W1t   = W1p + (size_t)1024 * 384;    // 4,096
    float* WattT = W1t + 4096;                  // 13,312
    float* WoutT = WattT + 13312;               // 32,768

    size_t zfloats = 4 * (size_t)BLK2 + 32;
    hipMemsetAsync(ws, 0, zfloats * sizeof(float), stream);
    pack_all<<<1204, 256, 0, stream>>>(Wih1, Whh1, b1, Watt, Wout,
                                       W1p, W1t, WattT, WoutT);

    void* args[] = {
        (void*)&W1p, (void*)&W1t, (void*)&Wih2, (void*)&Whh2, (void*)&b2,
        (void*)&Wih3, (void*)&Whh3, (void*)&b3,
        (void*)&WattT, (void*)&batt, (void*)&WoutT, (void*)&bout,
        (void*)&emb, (void*)&words, (void*)&wlen, (void*)&traj,
        (void*)&x2b, (void*)&x3b,
        (void*)&out, (void*)&barc
    };
    hipLaunchCooperativeKernel((void*)fused, dim3(NWG), dim3(NTHR),
                               args, 0, stream);
}

// Round 3
// 90211.334 us; speedup vs baseline: 1.7152x; 1.1220x over previous
//
#include <hip/hip_runtime.h>
#include <math.h>

#define Bn 256
#define Sn 1024
#define Ln 32
#define En 128
#define Hn 256
#define Mn 10
#define OUTn 121
#define K1 387
#define BLK2 (Bn * 640)   // one slot of x2/x3 (rows stride 640)
#define NWG 256
#define NTHR 768
#define CO 0x11           // aux cache policy: SC0|SC1 = device-coherent (gfx940+)

typedef float f32x4 __attribute__((ext_vector_type(4)));
typedef int   i32x4 __attribute__((ext_vector_type(4)));

// CK-style raw buffer intrinsics (compiler tracks them -> auto s_waitcnt)
__device__ f32x4 llvm_amdgcn_raw_buffer_load_v4f32(i32x4 rsrc, int voff, int soff, int aux) __asm("llvm.amdgcn.raw.buffer.load.v4f32");
__device__ float llvm_amdgcn_raw_buffer_load_f32(i32x4 rsrc, int voff, int soff, int aux) __asm("llvm.amdgcn.raw.buffer.load.f32");
__device__ void  llvm_amdgcn_raw_buffer_store_v4f32(f32x4 d, i32x4 rsrc, int voff, int soff, int aux) __asm("llvm.amdgcn.raw.buffer.store.v4f32");
__device__ void  llvm_amdgcn_raw_buffer_store_f32(float d, i32x4 rsrc, int voff, int soff, int aux) __asm("llvm.amdgcn.raw.buffer.store.f32");

__device__ __forceinline__ i32x4 make_srd(const void* p) {
    i32x4 r;
    r.x = (int)((unsigned long long)p & 0xFFFFFFFFull);
    r.y = (int)((unsigned long long)p >> 32);   // stride=0
    r.z = -1;                                   // num_records = 0xFFFFFFFF
    r.w = 0x00020000;                           // raw dword access
    return r;
}

__device__ __forceinline__ float sigmoidf_(float x) {
    return 1.0f / (1.0f + __expf(-x));
}
__device__ __forceinline__ float tanhf_(float x) {
    return 1.0f - 2.0f / (__expf(2.0f * x) + 1.0f);
}
__device__ __forceinline__ float softplus_(float x) {
    return (x > 20.0f) ? x : log1pf(__expf(x));
}

// ---------------- pack (once per launch) ----------------
__global__ __launch_bounds__(256) void pack_all(
    const float* __restrict__ Wih1, const float* __restrict__ Whh1,
    const float* __restrict__ b1,
    const float* __restrict__ Watt, const float* __restrict__ Wout,
    float* __restrict__ W1p, float* __restrict__ W1t,
    float* __restrict__ WattT, float* __restrict__ WoutT)
{
    const int bid = blockIdx.x, tid = threadIdx.x;
    if (bid < 1024) {
        int r = bid, h = r >> 2, g = r & 3, row = g * 256 + h;
        for (int k = tid; k < 384; k += 256)
            W1p[(size_t)r * 384 + k] = (k < 256) ? Whh1[row * 256 + k]
                                                 : Wih1[row * 131 + (k - 256)];
        if (tid < 3) W1t[r * 4 + tid] = Wih1[row * 131 + 128 + tid];
        if (tid == 3) W1t[r * 4 + 3] = b1[row];
    } else if (bid < 1152) {
        int idx = (bid - 1024) * 256 + tid;        // 32768 = 256*128
        int k = idx >> 7, rr = idx & 127;
        WoutT[idx] = (rr < OUTn) ? Wout[rr * Hn + k] : 0.f;
    } else {
        int idx = (bid - 1152) * 256 + tid;        // 13312 = 416*32
        if (idx < 13312) {
            int k = idx >> 5, m = idx & 31;
            WattT[idx] = (m < 30 && k < K1) ? Watt[m * K1 + k] : 0.f;
        }
    }
}

// ---------------- dot: 4 gate-rows x 4 batches; W cached, X device-coherent --
template <int N4>
__device__ __forceinline__ void dotg(const float* __restrict__ Wb, int gs,
                                     i32x4 xrs, int xoff,
                                     float (&acc)[4][4])
{
#pragma unroll 4
    for (int kk = 0; kk < N4; ++kk) {
        f32x4 wv[4], xv[4];
#pragma unroll
        for (int g = 0; g < 4; ++g)
            wv[g] = *(const f32x4*)(Wb + (size_t)g * gs + (kk << 2));
#pragma unroll
        for (int bb = 0; bb < 4; ++bb)
            xv[bb] = llvm_amdgcn_raw_buffer_load_v4f32(xrs, xoff + bb * 2560 + (kk << 4), 0, CO);
#pragma unroll
        for (int g = 0; g < 4; ++g)
#pragma unroll
            for (int bb = 0; bb < 4; ++bb) {
                acc[g][bb] = fmaf(wv[g].x, xv[bb].x, acc[g][bb]);
                acc[g][bb] = fmaf(wv[g].y, xv[bb].y, acc[g][bb]);
                acc[g][bb] = fmaf(wv[g].z, xv[bb].z, acc[g][bb]);
                acc[g][bb] = fmaf(wv[g].w, xv[bb].w, acc[g][bb]);
            }
    }
}

// ---------------- grid barrier: contention-free slot barrier ----------------
// barc[0]          : epoch (published by WG0)
// barc[16+wg*16]   : per-WG arrival slot (64B apart -> zero RMW contention)
// Each WG's t0 stores its arrival epoch; WG0's first 256 threads poll one
// slot each, then t0 publishes epoch; all other WGs spin on epoch.
// All data moves via SC0|SC1 (device-coherent) accesses, so no cache
// maintenance is needed here — ordering only.
__device__ __forceinline__ void grid_sync(unsigned* barc, int wg, int tid,
                                          unsigned target)
{
    asm volatile("s_waitcnt vmcnt(0)" ::: "memory");
    __syncthreads();
    unsigned* epoch = barc;
    unsigned* arr   = barc + 16;
    if (tid == 0)
        __hip_atomic_store(&arr[wg * 16], target, __ATOMIC_RELAXED,
                           __HIP_MEMORY_SCOPE_AGENT);
    if (wg == 0) {
        if (tid < NWG) {
            while (__hip_atomic_load(&arr[tid * 16], __ATOMIC_RELAXED,
                                     __HIP_MEMORY_SCOPE_AGENT) < target)
                __builtin_amdgcn_s_sleep(1);
        }
        __syncthreads();
        if (tid == 0)
            __hip_atomic_store(epoch, target, __ATOMIC_RELAXED,
                               __HIP_MEMORY_SCOPE_AGENT);
    } else {
        if (tid == 0) {
            while (__hip_atomic_load(epoch, __ATOMIC_RELAXED,
                                     __HIP_MEMORY_SCOPE_AGENT) < target)
                __builtin_amdgcn_s_sleep(1);
        }
        __syncthreads();
    }
}

// ---------------- persistent fused kernel ----------------
__global__ __launch_bounds__(NTHR, 3) void fused(
    const float* __restrict__ W1p, const float* __restrict__ W1t,
    const float* __restrict__ Wih2, const float* __restrict__ Whh2,
    const float* __restrict__ b2,
    const float* __restrict__ Wih3, const float* __restrict__ Whh3,
    const float* __restrict__ b3,
    const float* __restrict__ WattT, const float* __restrict__ batt,
    const float* __restrict__ WoutT, const float* __restrict__ bout,
    const float* __restrict__ emb, const int* __restrict__ words,
    const int* __restrict__ wlen, const float* __restrict__ traj,
    float* __restrict__ x2b, float* __restrict__ x3b,
    float* __restrict__ out, unsigned* __restrict__ barc)
{
    const int wg  = blockIdx.x;
    const int tid = threadIdx.x;
    const int grp = tid >> 8;          // 0,1,2 = layer group for A-phase
    const int t   = tid & 255;

    __shared__ float red[3 * 4224];    // 50.7 KB
    __shared__ float attL[K1];
    __shared__ float buf[NTHR];
    __shared__ float pv[32];
    __shared__ float sal[Mn], srb[Mn], skp[Mn];
    __shared__ float phi[Ln + 1];
    __shared__ int   wintL[Ln];
    __shared__ float h3L[Hn];
    __shared__ int   lenL;

    if (tid < Ln) wintL[tid] = words[wg * Ln + tid];
    if (tid == 0) lenL = wlen[wg];

    // XCD-aware tile mapping: XCD = wg%8 (round-robin dispatch). Give each
    // XCD a fixed set of 4 h-tiles (all 8 b-tiles) so its ~850 KB weight
    // slice stays L2-resident across all 1024 steps.
    const int ht = (wg & 7) * 4 + ((wg >> 3) & 3);
    const int bt = wg >> 5;
    const int ks = t >> 6, tr = (t >> 3) & 7, tb = t & 7;

    const i32x4 rs2 = make_srd(x2b);
    const i32x4 rs3 = make_srd(x3b);

    unsigned bar = 0;

    float c_reg  = 0.f;    // LSTM cell state: (grp, hg, bg) fixed per thread
    float kp_reg = 0.f;    // kappa: thread tid<Mn of WG wg

    __syncthreads();

    for (int i = 0; i <= Sn + 1; ++i) {
        const int p = i & 1, q = (i + 1) & 1;

        // ================= A phase =================
        {
            const int l = grp;
            bool active;
            i32x4 d1rs = rs2, d2rs = rs3;
            int d1base = 0, d2base = 0;
            bool have2 = false;
            int xbase;                     // byte offset of X slot
            if (l == 0) {                  // gates1(i): X = x2(i-1)
                active = (i < Sn);
                xbase  = q * (BLK2 * 4);
                d1base = p * (BLK2 * 4);                 // h1(i) -> x2(i)[0:256)
            } else if (l == 1) {           // gates2(i-1)
                active = (i >= 1 && i <= Sn);
                xbase  = q * (BLK2 * 4);
                d1base = p * (BLK2 * 4) + 384 * 4;       // h2(i-1) -> x2(i)[384:)
                d2base = q * (BLK2 * 4);                 //         -> x3(i-1)[0:256)
                have2  = true;
            } else {                       // gates3(i-2)
                active = (i >= 2);
                xbase  = p * (BLK2 * 4);                 // (i-2)&1 == p
                d1rs   = rs3;
                d1base = q * (BLK2 * 4) + 384 * 4;       // h3(i-2) -> x3(i-1)[384:)
            }

            if (active) {
                float acc[4][4];
#pragma unroll
                for (int g = 0; g < 4; ++g)
#pragma unroll
                    for (int bb = 0; bb < 4; ++bb) acc[g][bb] = 0.f;

                const int xrow = xbase + (bt * 32 + tb * 4) * 2560;
                const int hd = ht * 8 + tr;
                if (l == 0) {
                    dotg<24>(W1p + (size_t)(hd * 4) * 384 + ks * 96, 384,
                             rs2, xrow + ks * 384, acc);
                } else {
                    const float* Wih = (l == 1) ? Wih2 : Wih3;
                    const float* Whh = (l == 1) ? Whh2 : Whh3;
                    const i32x4 xrs = (l == 1) ? rs2 : rs3;
                    if (ks < 2)
                        dotg<40>(Wih + (size_t)hd * 384 + ks * 160, 256 * 384,
                                 xrs, xrow + ks * 640, acc);
                    else if (ks == 2) {
                        dotg<16>(Wih + (size_t)hd * 384 + 320, 256 * 384,
                                 xrs, xrow + 1280, acc);  // floats [320,384)
                        dotg<24>(Whh + (size_t)hd * 256,       256 * 256,
                                 xrs, xrow + 1536, acc);  // floats [384,480)
                    } else
                        dotg<40>(Whh + (size_t)hd * 256 + 96,  256 * 256,
                                 xrs, xrow + 1920, acc);  // floats [480,640)
                }
                float* rd = red + l * 4224;
#pragma unroll
                for (int g = 0; g < 4; ++g)
#pragma unroll
                    for (int bb = 0; bb < 4; ++bb)
                        rd[ks * 1056 + (tr * 4 + g) * 33 + tb * 4 + bb] = acc[g][bb];
            }
            __syncthreads();
            if (active) {
                const float* rd = red + l * 4224;
                const int th = t >> 5, tbb = t & 31;
                const int hg = ht * 8 + th, bg = bt * 32 + tbb;
                float g4[4];
#pragma unroll
                for (int g = 0; g < 4; ++g) {
                    int rl = (th * 4 + g) * 33 + tbb;
                    g4[g] = rd[rl] + rd[1056 + rl] + rd[2112 + rl] + rd[3168 + rl];
                }
                if (l == 0) {
                    const float* tp = traj + ((size_t)bg * Sn + i) * 3;
                    float t0 = tp[0], t1 = tp[1], t2 = tp[2];
#pragma unroll
                    for (int g = 0; g < 4; ++g) {
                        f32x4 wt = *(const f32x4*)(W1t + (size_t)(hg * 4 + g) * 4);
                        g4[g] += wt.x * t0 + wt.y * t1 + wt.z * t2 + wt.w;
                    }
                } else {
                    const float* bb_ = (l == 1) ? b2 : b3;
#pragma unroll
                    for (int g = 0; g < 4; ++g) g4[g] += bb_[(g << 8) + hg];
                }
                float I = sigmoidf_(g4[0]);
                float F = sigmoidf_(g4[1]);
                float G = tanhf_(g4[2]);
                float O = sigmoidf_(g4[3]);
                float cn = fmaf(F, c_reg, I * G);
                c_reg = cn;
                float hn = O * tanhf_(cn);
                int hoff = (bg * 640 + hg) * 4;
                llvm_amdgcn_raw_buffer_store_f32(hn, d1rs, d1base + hoff, 0, CO);
                if (have2)
                    llvm_amdgcn_raw_buffer_store_f32(hn, d2rs, d2base + hoff, 0, CO);
            }
        }
        grid_sync(barc, wg, tid, ++bar);

        // ================= B phase =================
        if (i < Sn) {
            for (int k = tid; k < K1; k += NTHR) {
                float v;
                if (k < 128)                                      // wv(i-1)
                    v = llvm_amdgcn_raw_buffer_load_f32(
                            rs2, (q * BLK2 + wg * 640 + 256 + k) * 4, 0, CO);
                else if (k < 131)
                    v = traj[((size_t)wg * Sn + i) * 3 + (k - 128)];
                else                                              // h1(i)
                    v = llvm_amdgcn_raw_buffer_load_f32(
                            rs2, (p * BLK2 + wg * 640 + (k - 131)) * 4, 0, CO);
                attL[k] = v;
            }
            __syncthreads();
            {
                int m = tid & 31, kss = tid >> 5;            // kss 0..23
                int kb = kss * 17, ke = (kb + 17 < K1) ? kb + 17 : K1;
                float s = 0.f;
                for (int k = kb; k < ke; ++k)
                    s = fmaf(WattT[k * 32 + m], attL[k], s);
                buf[tid] = s;
            }
            __syncthreads();
            if (tid < 30) {
                float s = batt[tid];
#pragma unroll
                for (int kss = 0; kss < 24; ++kss) s += buf[kss * 32 + tid];
                pv[tid] = s;
            }
            __syncthreads();
            if (tid < Mn) {
                float a   = softplus_(pv[tid]);
                float bb_ = fmaxf(softplus_(pv[10 + tid]), 0.01f);
                kp_reg += softplus_(pv[20 + tid]) * 0.04f;
                sal[tid] = a; srb[tid] = 1.0f / bb_; skp[tid] = kp_reg;
            }
            __syncthreads();
            if (tid < Ln) {
                float ph = 0.f;
                if (tid < lenL) {
#pragma unroll
                    for (int m = 0; m < Mn; ++m) {
                        float d = skp[m] - (float)tid;
                        ph = fmaf(sal[m], __expf(-d * d * srb[m]), ph);
                    }
                }
                phi[tid] = ph;
            }
            __syncthreads();
            if (tid == 0) {
                float s = 0.f;
                for (int l = 0; l < Ln; ++l) s += phi[l];
                phi[Ln] = 1.0f / (s + 1e-8f);
            }
            __syncthreads();
            if (tid < En) {
                float inv = phi[Ln];
                float a = 0.f;
                for (int l = 0; l < Ln; ++l)
                    a = fmaf(phi[l], emb[wintL[l] * En + tid], a);
                a *= inv;
                int wvoff = (p * BLK2 + wg * 640 + 256 + tid) * 4;
                llvm_amdgcn_raw_buffer_store_f32(a, rs2, wvoff, 0, CO);  // wv(i)
                llvm_amdgcn_raw_buffer_store_f32(a, rs3, wvoff, 0, CO);
            }
        }
        __syncthreads();
        if (i >= 2) {
            for (int k = tid; k < Hn; k += NTHR)
                h3L[k] = llvm_amdgcn_raw_buffer_load_f32(
                             rs3, (q * BLK2 + wg * 640 + 384 + k) * 4, 0, CO);
            __syncthreads();
            {
                int r = tid & 127, part = tid >> 7;          // part 0..5
                int kb = part * 43, ke = (kb + 43 < Hn) ? kb + 43 : Hn;
                float s = 0.f;
                for (int k = kb; k < ke; ++k)
                    s = fmaf(WoutT[k * 128 + r], h3L[k], s);
                buf[tid] = s;
            }
            __syncthreads();
            if (tid < OUTn) {
                float s = bout[tid];
#pragma unroll
                for (int j = 0; j < 6; ++j) s += buf[j * 128 + tid];
                out[((size_t)wg * Sn + (i - 2)) * OUTn + tid] = s;
            }
        }
        grid_sync(barc, wg, tid, ++bar);
    }
}

extern "C" void kernel_launch(void* const* d_in, const int* in_sizes, int n_in,
                              void* d_out, int out_size, void* d_ws, size_t ws_size,
                              hipStream_t stream)
{
    const float* traj  = (const float*)d_in[0];
    const int*   words = (const int*)d_in[1];
    const int*   wlen  = (const int*)d_in[2];
    const float* emb   = (const float*)d_in[3];
    const float* Wih1  = (const float*)d_in[4];
    const float* Whh1  = (const float*)d_in[5];
    const float* b1    = (const float*)d_in[6];
    const float* Wih2  = (const float*)d_in[7];
    const float* Whh2  = (const float*)d_in[8];
    const float* b2    = (const float*)d_in[9];
    const float* Wih3  = (const float*)d_in[10];
    const float* Whh3  = (const float*)d_in[11];
    const float* b3    = (const float*)d_in[12];
    const float* Watt  = (const float*)d_in[13];
    const float* batt  = (const float*)d_in[14];
    const float* Wout  = (const float*)d_in[15];
    const float* bout  = (const float*)d_in[16];
    float* out = (float*)d_out;

    // ws layout (floats/uints, 4B units)
    float* ws    = (float*)d_ws;
    float* x2b   = ws;                          // 2*BLK2 = 327,680
    float* x3b   = x2b + 2 * (size_t)BLK2;      // 327,680
    unsigned* barc = (unsigned*)(x3b + 2 * (size_t)BLK2); // 4352 uints (epoch + 256 slots)
    float* W1p   = x3b + 2 * (size_t)BLK2 + 4352; // 393,216
    float* W1t   = W1p + (size_t)1024 * 384;    // 4,096
    float* WattT = W1t + 4096;                  // 13,312
    float* WoutT = WattT + 13312;               // 32,768

    size_t zfloats = 4 * (size_t)BLK2 + 4352;
    hipMemsetAsync(ws, 0, zfloats * sizeof(float), stream);
    pack_all<<<1204, 256, 0, stream>>>(Wih1, Whh1, b1, Watt, Wout,
                                       W1p, W1t, WattT, WoutT);

    void* args[] = {
        (void*)&W1p, (void*)&W1t, (void*)&Wih2, (void*)&Whh2, (void*)&b2,
        (void*)&Wih3, (void*)&Whh3, (void*)&b3,
        (void*)&WattT, (void*)&batt, (void*)&WoutT, (void*)&bout,
        (void*)&emb, (void*)&words, (void*)&wlen, (void*)&traj,
        (void*)&x2b, (void*)&x3b,
        (void*)&out, (void*)&barc
    };
    hipLaunchCooperativeKernel((void*)fused, dim3(NWG), dim3(NTHR),
                               args, 0, stream);
}

// Round 4
// 52857.184 us; speedup vs baseline: 2.9273x; 1.7067x over previous
//
#include <hip/hip_runtime.h>
#include <math.h>

#define Bn 256
#define Sn 1024
#define Ln 32
#define En 128
#define Hn 256
#define Mn 10
#define OUTn 121
#define K1 387
#define BLK2 (Bn * 640)   // one slot of x2/x3 (rows stride 640)
#define NWG 256
#define NTHR 768
#define CO 0x11           // aux cache policy: SC0|SC1 = device-coherent (gfx940+)

typedef float f32x4 __attribute__((ext_vector_type(4)));
typedef int   i32x4 __attribute__((ext_vector_type(4)));

// CK-style raw buffer intrinsics (compiler tracks them -> auto s_waitcnt)
__device__ f32x4 llvm_amdgcn_raw_buffer_load_v4f32(i32x4 rsrc, int voff, int soff, int aux) __asm("llvm.amdgcn.raw.buffer.load.v4f32");
__device__ float llvm_amdgcn_raw_buffer_load_f32(i32x4 rsrc, int voff, int soff, int aux) __asm("llvm.amdgcn.raw.buffer.load.f32");
__device__ void  llvm_amdgcn_raw_buffer_store_f32(float d, i32x4 rsrc, int voff, int soff, int aux) __asm("llvm.amdgcn.raw.buffer.store.f32");

__device__ __forceinline__ i32x4 make_srd(const void* p) {
    i32x4 r;
    r.x = (int)((unsigned long long)p & 0xFFFFFFFFull);
    r.y = (int)((unsigned long long)p >> 32);   // stride=0
    r.z = -1;                                   // num_records = 0xFFFFFFFF
    r.w = 0x00020000;                           // raw dword access
    return r;
}

__device__ __forceinline__ float sigmoidf_(float x) {
    return 1.0f / (1.0f + __expf(-x));
}
__device__ __forceinline__ float tanhf_(float x) {
    return 1.0f - 2.0f / (__expf(2.0f * x) + 1.0f);
}
__device__ __forceinline__ float softplus_(float x) {
    return (x > 20.0f) ? x : log1pf(__expf(x));
}

// ---------------- pack (once per launch) ----------------
__global__ __launch_bounds__(256) void pack_all(
    const float* __restrict__ Wih1, const float* __restrict__ Whh1,
    const float* __restrict__ b1,
    const float* __restrict__ Watt, const float* __restrict__ Wout,
    float* __restrict__ W1p, float* __restrict__ W1t,
    float* __restrict__ WattT, float* __restrict__ WoutT)
{
    const int bid = blockIdx.x, tid = threadIdx.x;
    if (bid < 1024) {
        int r = bid, h = r >> 2, g = r & 3, row = g * 256 + h;
        for (int k = tid; k < 384; k += 256)
            W1p[(size_t)r * 384 + k] = (k < 256) ? Whh1[row * 256 + k]
                                                 : Wih1[row * 131 + (k - 256)];
        if (tid < 3) W1t[r * 4 + tid] = Wih1[row * 131 + 128 + tid];
        if (tid == 3) W1t[r * 4 + 3] = b1[row];
    } else if (bid < 1152) {
        int idx = (bid - 1024) * 256 + tid;        // 32768 = 256*128
        int k = idx >> 7, rr = idx & 127;
        WoutT[idx] = (rr < OUTn) ? Wout[rr * Hn + k] : 0.f;
    } else {
        int idx = (bid - 1152) * 256 + tid;        // 13312 = 416*32
        if (idx < 13312) {
            int k = idx >> 5, m = idx & 31;
            WattT[idx] = (m < 30 && k < K1) ? Watt[m * K1 + k] : 0.f;
        }
    }
}

// ---------------- chunked X staging: global(coherent) -> LDS ----------------
// Chunk = cols [c*64, c*64+64) of both the x2 tile and the x3 tile
// (32 rows each). 1024 16B-units per chunk; threads 0..767 take unit tid,
// threads 0..255 also take unit 768+tid. Contiguous per-wave -> full-line
// MALL requests. LDS layout: [row][64] with quad swizzle cq^((row>>2)&7).
__device__ __forceinline__ f32x4 ld_unit(int u, int c, int bt, int b2, int b3,
                                         i32x4 rs2, i32x4 rs3)
{
    int which = u >> 9, v = u & 511, row = v >> 4, seg = v & 15;
    int off = (which ? b3 : b2) + (((bt * 32 + row) * 640) + c * 64 + seg * 4) * 4;
    return llvm_amdgcn_raw_buffer_load_v4f32(which ? rs3 : rs2, off, 0, CO);
}
__device__ __forceinline__ void st_unit(int u, float* xls2, float* xls3, f32x4 d)
{
    int which = u >> 9, v = u & 511, row = v >> 4, seg = v & 15;
    float* dst = (which ? xls3 : xls2) + row * 64 + ((seg ^ ((row >> 2) & 7)) << 2);
    *(f32x4*)dst = d;
}

// ---------------- dot from LDS: 4 gate-rows x 4 batches, 16 cols ------------
// Thread's k-slice within the chunk: cols [ks*16, ks*16+16).
__device__ __forceinline__ void dot_lds(const float* __restrict__ Wb, int gs,
                                        const float* __restrict__ xls,
                                        int ks, int tb, float (&acc)[4][4])
{
#pragma unroll
    for (int j = 0; j < 4; ++j) {
        const int cq = ks * 4 + j;
        f32x4 wv[4], xv[4];
#pragma unroll
        for (int g = 0; g < 4; ++g)
            wv[g] = *(const f32x4*)(Wb + (size_t)g * gs + (cq << 2));
        const int xc = ((cq ^ tb) << 2);           // (row>>2)&7 == tb for our rows
#pragma unroll
        for (int bb = 0; bb < 4; ++bb)
            xv[bb] = *(const f32x4*)(xls + (tb * 4 + bb) * 64 + xc);
#pragma unroll
        for (int g = 0; g < 4; ++g)
#pragma unroll
            for (int bb = 0; bb < 4; ++bb) {
                acc[g][bb] = fmaf(wv[g].x, xv[bb].x, acc[g][bb]);
                acc[g][bb] = fmaf(wv[g].y, xv[bb].y, acc[g][bb]);
                acc[g][bb] = fmaf(wv[g].z, xv[bb].z, acc[g][bb]);
                acc[g][bb] = fmaf(wv[g].w, xv[bb].w, acc[g][bb]);
            }
    }
}

// ---------------- grid barrier: contention-free slot barrier ----------------
__device__ __forceinline__ void grid_sync(unsigned* barc, int wg, int tid,
                                          unsigned target)
{
    asm volatile("s_waitcnt vmcnt(0)" ::: "memory");
    __syncthreads();
    unsigned* epoch = barc;
    unsigned* arr   = barc + 16;
    if (tid == 0)
        __hip_atomic_store(&arr[wg * 16], target, __ATOMIC_RELAXED,
                           __HIP_MEMORY_SCOPE_AGENT);
    if (wg == 0) {
        if (tid < NWG) {
            while (__hip_atomic_load(&arr[tid * 16], __ATOMIC_RELAXED,
                                     __HIP_MEMORY_SCOPE_AGENT) < target)
                __builtin_amdgcn_s_sleep(1);
        }
        __syncthreads();
        if (tid == 0)
            __hip_atomic_store(epoch, target, __ATOMIC_RELAXED,
                               __HIP_MEMORY_SCOPE_AGENT);
    } else {
        if (tid == 0) {
            while (__hip_atomic_load(epoch, __ATOMIC_RELAXED,
                                     __HIP_MEMORY_SCOPE_AGENT) < target)
                __builtin_amdgcn_s_sleep(1);
        }
        __syncthreads();
    }
}

// ---------------- persistent fused kernel ----------------
__global__ __launch_bounds__(NTHR, 3) void fused(
    const float* __restrict__ W1p, const float* __restrict__ W1t,
    const float* __restrict__ Wih2, const float* __restrict__ Whh2,
    const float* __restrict__ b2,
    const float* __restrict__ Wih3, const float* __restrict__ Whh3,
    const float* __restrict__ b3,
    const float* __restrict__ WattT, const float* __restrict__ batt,
    const float* __restrict__ WoutT, const float* __restrict__ bout,
    const float* __restrict__ emb, const int* __restrict__ words,
    const int* __restrict__ wlen, const float* __restrict__ traj,
    float* __restrict__ x2b, float* __restrict__ x3b,
    float* __restrict__ out, unsigned* __restrict__ barc)
{
    const int wg  = blockIdx.x;
    const int tid = threadIdx.x;
    const int grp = tid >> 8;          // 0,1,2 = layer group for A-phase
    const int t   = tid & 255;

    __shared__ float red[3 * 4224];    // 50.7 KB; chunk buffers alias [0:4096)
    __shared__ float attL[K1];
    __shared__ float buf[NTHR];
    __shared__ float pv[32];
    __shared__ float sal[Mn], srb[Mn], skp[Mn];
    __shared__ float phi[Ln + 1];
    __shared__ int   wintL[Ln];
    __shared__ float h3L[Hn];
    __shared__ int   lenL;

    float* xls2 = red;                 // 32x64 chunk of x2 tile (aliases red)
    float* xls3 = red + 2048;          // 32x64 chunk of x3 tile

    if (tid < Ln) wintL[tid] = words[wg * Ln + tid];
    if (tid == 0) lenL = wlen[wg];

    // XCD-aware tile mapping: each XCD owns 4 h-tiles -> weights L2-resident.
    const int ht = (wg & 7) * 4 + ((wg >> 3) & 3);
    const int bt = wg >> 5;
    const int ks = t >> 6, tr = (t >> 3) & 7, tb = t & 7;
    const int hd = ht * 8 + tr;

    const i32x4 rs2 = make_srd(x2b);
    const i32x4 rs3 = make_srd(x3b);

    const int u0 = tid;                // staging unit assignments
    const int u1 = 768 + tid;
    const bool hb = (tid < 256);

    unsigned bar = 0;

    float c_reg  = 0.f;    // LSTM cell state: (grp, hg, bg) fixed per thread
    float kp_reg = 0.f;    // kappa: thread tid<Mn of WG wg

    __syncthreads();

    for (int i = 0; i <= Sn + 1; ++i) {
        const int p = i & 1, q = (i + 1) & 1;

        // ================= A phase =================
        {
            const int l = grp;
            bool active;
            i32x4 d1rs = rs2, d2rs = rs3;
            int d1base = 0, d2base = 0;
            bool have2 = false;
            if (l == 0) {                  // gates1(i): X = x2(i-1)
                active = (i < Sn);
                d1base = p * (BLK2 * 4);                 // h1(i) -> x2(i)[0:256)
            } else if (l == 1) {           // gates2(i-1): X = x2(i-1)
                active = (i >= 1 && i <= Sn);
                d1base = p * (BLK2 * 4) + 384 * 4;       // h2(i-1) -> x2(i)[384:)
                d2base = q * (BLK2 * 4);                 //         -> x3(i-1)[0:256)
                have2  = true;
            } else {                       // gates3(i-2): X = x3(i-2)
                active = (i >= 2);
                d1rs   = rs3;
                d1base = q * (BLK2 * 4) + 384 * 4;       // h3(i-2) -> x3(i-1)[384:)
            }

            float acc[4][4];
#pragma unroll
            for (int g = 0; g < 4; ++g)
#pragma unroll
                for (int bb = 0; bb < 4; ++bb) acc[g][bb] = 0.f;

            const int b2base = q * (BLK2 * 4);   // x2(i-1) slot (read)
            const int b3base = p * (BLK2 * 4);   // x3(i-2) slot (read)

            // pipelined chunk staging: loads for c+1 fly during compute of c
            f32x4 ra = ld_unit(u0, 0, bt, b2base, b3base, rs2, rs3);
            f32x4 rb = {0.f, 0.f, 0.f, 0.f};
            if (hb) rb = ld_unit(u1, 0, bt, b2base, b3base, rs2, rs3);

            for (int c = 0; c < 10; ++c) {
                __syncthreads();               // prev compute done reading xls
                st_unit(u0, xls2, xls3, ra);
                if (hb) st_unit(u1, xls2, xls3, rb);
                if (c + 1 < 10) {
                    ra = ld_unit(u0, c + 1, bt, b2base, b3base, rs2, rs3);
                    if (hb) rb = ld_unit(u1, c + 1, bt, b2base, b3base, rs2, rs3);
                }
                __syncthreads();               // staged chunk visible
                if (active) {
                    const float* Wb = nullptr; int gs = 0;
                    const float* xls = (l == 2) ? xls3 : xls2;
                    if (l == 0) {
                        if (c < 6) { Wb = W1p + (size_t)(hd * 4) * 384 + c * 64; gs = 384; }
                    } else {
                        const float* Wih = (l == 1) ? Wih2 : Wih3;
                        const float* Whh = (l == 1) ? Whh2 : Whh3;
                        if (c < 6) { Wb = Wih + (size_t)hd * 384 + c * 64; gs = 256 * 384; }
                        else       { Wb = Whh + (size_t)hd * 256 + (c - 6) * 64; gs = 256 * 256; }
                    }
                    if (Wb) dot_lds(Wb, gs, xls, ks, tb, acc);
                }
            }
            __syncthreads();                   // xls reads done before red write

            if (active) {
                float* rd = red + l * 4224;
                // col permutation tb + 8*bb: 2-way max bank aliasing (free)
#pragma unroll
                for (int g = 0; g < 4; ++g)
#pragma unroll
                    for (int bb = 0; bb < 4; ++bb)
                        rd[ks * 1056 + (tr * 4 + g) * 33 + tb + 8 * bb] = acc[g][bb];
            }
            __syncthreads();
            if (active) {
                const float* rd = red + l * 4224;
                const int th = t & 7, tbb = t >> 3;      // lanes 0..7 -> consec h
                const int hg = ht * 8 + th, bg = bt * 32 + tbb;
                const int cp = (tbb >> 2) + 8 * (tbb & 3);
                float g4[4];
#pragma unroll
                for (int g = 0; g < 4; ++g) {
                    int rl = (th * 4 + g) * 33 + cp;
                    g4[g] = rd[rl] + rd[1056 + rl] + rd[2112 + rl] + rd[3168 + rl];
                }
                if (l == 0) {
                    const float* tp = traj + ((size_t)bg * Sn + i) * 3;
                    float t0 = tp[0], t1 = tp[1], t2 = tp[2];
#pragma unroll
                    for (int g = 0; g < 4; ++g) {
                        f32x4 wt = *(const f32x4*)(W1t + (size_t)(hg * 4 + g) * 4);
                        g4[g] += wt.x * t0 + wt.y * t1 + wt.z * t2 + wt.w;
                    }
                } else {
                    const float* bb_ = (l == 1) ? b2 : b3;
#pragma unroll
                    for (int g = 0; g < 4; ++g) g4[g] += bb_[(g << 8) + hg];
                }
                float I = sigmoidf_(g4[0]);
                float F = sigmoidf_(g4[1]);
                float G = tanhf_(g4[2]);
                float O = sigmoidf_(g4[3]);
                float cn = fmaf(F, c_reg, I * G);
                c_reg = cn;
                float hn = O * tanhf_(cn);
                int hoff = (bg * 640 + hg) * 4;
                llvm_amdgcn_raw_buffer_store_f32(hn, d1rs, d1base + hoff, 0, CO);
                if (have2)
                    llvm_amdgcn_raw_buffer_store_f32(hn, d2rs, d2base + hoff, 0, CO);
            }
        }
        grid_sync(barc, wg, tid, ++bar);

        // ================= B phase =================
        if (i < Sn) {
            for (int k = tid; k < K1; k += NTHR) {
                float v;
                if (k < 128)                                      // wv(i-1)
                    v = llvm_amdgcn_raw_buffer_load_f32(
                            rs2, (q * BLK2 + wg * 640 + 256 + k) * 4, 0, CO);
                else if (k < 131)
                    v = traj[((size_t)wg * Sn + i) * 3 + (k - 128)];
                else                                              // h1(i)
                    v = llvm_amdgcn_raw_buffer_load_f32(
                            rs2, (p * BLK2 + wg * 640 + (k - 131)) * 4, 0, CO);
                attL[k] = v;
            }
            __syncthreads();
            {
                int m = tid & 31, kss = tid >> 5;            // kss 0..23
                int kb = kss * 17, ke = (kb + 17 < K1) ? kb + 17 : K1;
                float s = 0.f;
                for (int k = kb; k < ke; ++k)
                    s = fmaf(WattT[k * 32 + m], attL[k], s);
                buf[tid] = s;
            }
            __syncthreads();
            if (tid < 30) {
                float s = batt[tid];
#pragma unroll
                for (int kss = 0; kss < 24; ++kss) s += buf[kss * 32 + tid];
                pv[tid] = s;
            }
            __syncthreads();
            if (tid < Mn) {
                float a   = softplus_(pv[tid]);
                float bb_ = fmaxf(softplus_(pv[10 + tid]), 0.01f);
                kp_reg += softplus_(pv[20 + tid]) * 0.04f;
                sal[tid] = a; srb[tid] = 1.0f / bb_; skp[tid] = kp_reg;
            }
            __syncthreads();
            if (tid < Ln) {
                float ph = 0.f;
                if (tid < lenL) {
#pragma unroll
                    for (int m = 0; m < Mn; ++m) {
                        float d = skp[m] - (float)tid;
                        ph = fmaf(sal[m], __expf(-d * d * srb[m]), ph);
                    }
                }
                phi[tid] = ph;
            }
            __syncthreads();
            if (tid == 0) {
                float s = 0.f;
                for (int l = 0; l < Ln; ++l) s += phi[l];
                phi[Ln] = 1.0f / (s + 1e-8f);
            }
            __syncthreads();
            if (tid < En) {
                float inv = phi[Ln];
                float a = 0.f;
                for (int l = 0; l < Ln; ++l)
                    a = fmaf(phi[l], emb[wintL[l] * En + tid], a);
                a *= inv;
                int wvoff = (p * BLK2 + wg * 640 + 256 + tid) * 4;
                llvm_amdgcn_raw_buffer_store_f32(a, rs2, wvoff, 0, CO);  // wv(i)
                llvm_amdgcn_raw_buffer_store_f32(a, rs3, wvoff, 0, CO);
            }
        }
        __syncthreads();
        if (i >= 2) {
            for (int k = tid; k < Hn; k += NTHR)
                h3L[k] = llvm_amdgcn_raw_buffer_load_f32(
                             rs3, (q * BLK2 + wg * 640 + 384 + k) * 4, 0, CO);
            __syncthreads();
            {
                int r = tid & 127, part = tid >> 7;          // part 0..5
                int kb = part * 43, ke = (kb + 43 < Hn) ? kb + 43 : Hn;
                float s = 0.f;
                for (int k = kb; k < ke; ++k)
                    s = fmaf(WoutT[k * 128 + r], h3L[k], s);
                buf[tid] = s;
            }
            __syncthreads();
            if (tid < OUTn) {
                float s = bout[tid];
#pragma unroll
                for (int j = 0; j < 6; ++j) s += buf[j * 128 + tid];
                out[((size_t)wg * Sn + (i - 2)) * OUTn + tid] = s;
            }
        }
        grid_sync(barc, wg, tid, ++bar);
    }
}

extern "C" void kernel_launch(void* const* d_in, const int* in_sizes, int n_in,
                              void* d_out, int out_size, void* d_ws, size_t ws_size,
                              hipStream_t stream)
{
    const float* traj  = (const float*)d_in[0];
    const int*   words = (const int*)d_in[1];
    const int*   wlen  = (const int*)d_in[2];
    const float* emb   = (const float*)d_in[3];
    const float* Wih1  = (const float*)d_in[4];
    const float* Whh1  = (const float*)d_in[5];
    const float* b1    = (const float*)d_in[6];
    const float* Wih2  = (const float*)d_in[7];
    const float* Whh2  = (const float*)d_in[8];
    const float* b2    = (const float*)d_in[9];
    const float* Wih3  = (const float*)d_in[10];
    const float* Whh3  = (const float*)d_in[11];
    const float* b3    = (const float*)d_in[12];
    const float* Watt  = (const float*)d_in[13];
    const float* batt  = (const float*)d_in[14];
    const float* Wout  = (const float*)d_in[15];
    const float* bout  = (const float*)d_in[16];
    float* out = (float*)d_out;

    // ws layout (floats/uints, 4B units)
    float* ws    = (float*)d_ws;
    float* x2b   = ws;                          // 2*BLK2 = 327,680
    float* x3b   = x2b + 2 * (size_t)BLK2;      // 327,680
    unsigned* barc = (unsigned*)(x3b + 2 * (size_t)BLK2); // 4352 uints
    float* W1p   = x3b + 2 * (size_t)BLK2 + 4352; // 393,216
    float* W1t   = W1p + (size_t)1024 * 384;    // 4,096
    float* WattT = W1t + 4096;                  // 13,312
    float* WoutT = WattT + 13312;               // 32,768

    size_t zfloats = 4 * (size_t)BLK2 + 4352;
    hipMemsetAsync(ws, 0, zfloats * sizeof(float), stream);
    pack_all<<<1204, 256, 0, stream>>>(Wih1, Whh1, b1, Watt, Wout,
                                       W1p, W1t, WattT, WoutT);

    void* args[] = {
        (void*)&W1p, (void*)&W1t, (void*)&Wih2, (void*)&Whh2, (void*)&b2,
        (void*)&Wih3, (void*)&Whh3, (void*)&b3,
        (void*)&WattT, (void*)&batt, (void*)&WoutT, (void*)&bout,
        (void*)&emb, (void*)&words, (void*)&wlen, (void*)&traj,
        (void*)&x2b, (void*)&x3b,
        (void*)&out, (void*)&barc
    };
    hipLaunchCooperativeKernel((void*)fused, dim3(NWG), dim3(NTHR),
                               args, 0, stream);
}